// Round 3
// baseline (370.369 us; speedup 1.0000x reference)
//
#include <hip/hip_runtime.h>
#include <hip/hip_bf16.h>
#include <stdint.h>

typedef _Float16 f16;
typedef _Float16 f16x8 __attribute__((ext_vector_type(8)));
typedef float f32x16 __attribute__((ext_vector_type(16)));
typedef float f32x4 __attribute__((ext_vector_type(4)));
typedef uint32_t u32x4 __attribute__((ext_vector_type(4)));
typedef uint32_t u32x2 __attribute__((ext_vector_type(2)));

// async global->LDS, 16B per lane, lands at ldsbase + lane*16 (wave-uniform base)
#define GLL16(gp, lp)                                                          \
  __builtin_amdgcn_global_load_lds(                                            \
      (const __attribute__((address_space(1))) void*)(gp),                     \
      (__attribute__((address_space(3))) void*)(lp), 16, 0, 0)

// s_waitcnt vmcnt(N), lgkm/exp unconstrained. gfx9 encoding.
#define WAITCNT_VM(N)                                                          \
  __builtin_amdgcn_s_waitcnt(((N)&0xF) | ((((N) >> 4) & 3) << 14) | 0x0F70)

// ---------------------------------------------------------------------------
// Kernel 1: x NCHW f32 [32,256,64,64] -> xt NHWC f16 [32,64,64,256]
// One (b,h) slice per block. LDS tile 64 w-rows x 128 u32 (32 KB), position
// swizzle u' = u ^ (4*((w>>2)&7)): keeps b64-write pairs and b128-read quads
// contiguous; spreads write banks ~4-way (vs 8-way before), reads dense.
// ---------------------------------------------------------------------------
__global__ __launch_bounds__(256) void nchw_to_nhwc_f16(
    const float* __restrict__ x, f16* __restrict__ xt) {
  __shared__ __align__(16) uint32_t tile[64 * 128];  // 32768 B
  const int bh = blockIdx.x;  // b*64 + h
  const int t = threadIdx.x;
  const float* src = x + (size_t)(bh >> 6) * (256 * 4096) + (bh & 63) * 64;

  const int w4 = t & 15;            // float4 index along w
  const int cq = t >> 4;            // c-quad 0..15
  const int xorv = 4 * (w4 & 7);    // = 4*((w>>2)&7) since w = w4*4+jw
#pragma unroll
  for (int it = 0; it < 4; ++it) {
    const int c0 = it * 64 + cq * 4;
    float4 v0 = *(const float4*)(src + (size_t)(c0 + 0) * 4096 + w4 * 4);
    float4 v1 = *(const float4*)(src + (size_t)(c0 + 1) * 4096 + w4 * 4);
    float4 v2 = *(const float4*)(src + (size_t)(c0 + 2) * 4096 + w4 * 4);
    float4 v3 = *(const float4*)(src + (size_t)(c0 + 3) * 4096 + w4 * 4);
    const float* p0 = (const float*)&v0;
    const float* p1 = (const float*)&v1;
    const float* p2 = (const float*)&v2;
    const float* p3 = (const float*)&v3;
    const int u = it * 32 + cq * 2;  // even word index (c-pair)
#pragma unroll
    for (int jw = 0; jw < 4; ++jw) {
      const int w = w4 * 4 + jw;
      f16 h0 = (f16)p0[jw], h1 = (f16)p1[jw], h2 = (f16)p2[jw], h3 = (f16)p3[jw];
      uint32_t lo = (uint32_t)__builtin_bit_cast(uint16_t, h0) |
                    ((uint32_t)__builtin_bit_cast(uint16_t, h1) << 16);
      uint32_t hi = (uint32_t)__builtin_bit_cast(uint16_t, h2) |
                    ((uint32_t)__builtin_bit_cast(uint16_t, h3) << 16);
      u32x2 pk = {lo, hi};
      *(u32x2*)&tile[w * 128 + (u ^ xorv)] = pk;
    }
  }
  __syncthreads();
  f16* dst = xt + (size_t)bh * 16384;
#pragma unroll
  for (int it = 0; it < 8; ++it) {
    const int idx = it * 256 + t;  // 0..2047 16B-granules
    const int w = idx >> 5;
    const int g = idx & 31;
    const u32x4 v = *(const u32x4*)&tile[w * 128 + ((g * 4) ^ (4 * ((w >> 2) & 7)))];
    *(u32x4*)(dst + idx * 8) = v;
  }
}

// ---------------------------------------------------------------------------
// Kernel 2: W [32co][256ci][9][9] f32 -> wt [81 kk][8 cic][32 co][32 ci] f16
// Coalesced reads (contiguous 10368-f32 slab per block) + LDS gather.
// 64 blocks = 32 co x 2 ci-halves.
// ---------------------------------------------------------------------------
__global__ __launch_bounds__(256) void pack_w(const float* __restrict__ W,
                                              f16* __restrict__ wt) {
  __shared__ float lds[10368];  // [128 ci][81 kk]
  const int t = threadIdx.x;
  const int co = blockIdx.x >> 1;
  const int cih = blockIdx.x & 1;
  const float* src = W + (size_t)(co * 256 + cih * 128) * 81;
  for (int i = t; i < 10368; i += 256) lds[i] = src[i];
  __syncthreads();
  for (int j = t; j < 1296; j += 256) {
    const int kk = j >> 4;
    const int t16 = j & 15;
    const int cicl = t16 >> 2;       // 0..3 (cic within half)
    const int ci8 = (t16 & 3) * 8;   // 0,8,16,24
    f16 tmp[8];
#pragma unroll
    for (int e = 0; e < 8; ++e)
      tmp[e] = (f16)lds[(cicl * 32 + ci8 + e) * 81 + kk];
    *(f16x8*)&wt[(size_t)kk * 8192 + (cih * 4 + cicl) * 1024 + co * 32 + ci8] =
        *(f16x8*)tmp;
  }
}

// ---------------------------------------------------------------------------
// Kernel 3: implicit-GEMM conv, mfma_f32_32x32x16_f16, M32 tiles.
// 3136 blocks = 784 M32-tiles x 4 kg; 4 waves/block; q = kg*4+wave owns
// cic32-chunks [floor(81q/2), floor(81(q+1))/2) of 648 total (40/41 each).
// A: per-chunk 2 KB via global_load_lds double-buffer, granule rotation by
// (row>>1)&3 for dense-optimal ds_read_b128 banks. B: global->VGPR (L2-hot),
// 1-iter prefetch. No barriers in K-loop; s_waitcnt vmcnt(4).
// 16.9 KB LDS + <=64 VGPR -> 8 blocks/CU resident; 12.25 blocks/CU of work.
// ---------------------------------------------------------------------------
__global__ __launch_bounds__(256, 8) void conv_gemm(const f16* __restrict__ xt,
                                                    const f16* __restrict__ wt,
                                                    float* __restrict__ convp) {
  __shared__ __align__(16) char smem[16896];  // max(4*4096 staging, red 16896)
  const int tid = threadIdx.x;
  const int lane = tid & 63;
  const int wave = tid >> 6;
  const int blk = blockIdx.x;
  // XCD affinity: all 4 kg's of a mtile slice land on one XCD (L2 reuse).
  const int xcd = blk & 7;
  const int j = blk >> 3;           // 0..391
  const int kg = j / 98;            // 0..3
  const int mtile = xcd * 98 + (j - kg * 98);  // 0..783
  const int q = kg * 4 + wave;      // 0..15
  const int cstart = (81 * q) >> 1;
  const int nIt = ((81 * (q + 1)) >> 1) - cstart;  // 40 or 41

  // A staging: lane -> row r = i*16 + (lane>>2), granule pos q4 = lane&3.
  // pos q4 holds granule (q4 + rot)&3, rot = (r>>1)&3 = (lane>>3)&3.
  const int rot = (lane >> 3) & 3;
  const int g = ((lane & 3) + rot) & 3;
  int pb[2];
#pragma unroll
  for (int i = 0; i < 2; ++i) {
    const int r = i * 16 + (lane >> 2);
    const int p = mtile * 32 + r;   // 0..25087 exact (784*32)
    const int bi = p / 784;
    const int rm = p - bi * 784;
    const int oh = rm / 28;
    const int ow = rm - oh * 28;
    pb[i] = (bi * 4096 + oh * 128 + ow * 2) * 512 + g * 16;
  }
  const char* xtb = (const char*)xt;
  const char* wtb = (const char*)wt;
  char* lws = smem + wave * 4096;

  // Fragment read offsets: granule wanted for k-step s is 2s+h (h=lane>>5),
  // stored at pos (granule - rot_m)&3, rot_m = (m>>1)&3.
  const int m = lane & 31;
  const int h = lane >> 5;
  const int mrot = (m >> 1) & 3;
  const int offA0 = m * 64 + (((0 + h) - mrot) & 3) * 16;
  const int offA1 = m * 64 + (((2 + h) - mrot) & 3) * 16;
  const char* bbase = wtb + m * 64 + h * 16;

  f32x16 acc;
#pragma unroll
  for (int i = 0; i < 16; ++i) acc[i] = 0.f;

  auto stage = [&](int c, int par) {
    const int kk = c >> 3;
    const int cic = c & 7;
    const int kh = (kk * 57) >> 9;  // kk/9 for kk<=80
    const int kw = kk - kh * 9;
    const int koff = (kh * 64 + kw) * 512 + cic * 64;
    char* lb = lws + par * 2048;
    GLL16(xtb + (pb[0] + koff), lb);
    GLL16(xtb + (pb[1] + koff), lb + 1024);
  };
  auto bload = [&](int c, int s) -> f16x8 {
    return *(const f16x8*)(bbase + (size_t)(c >> 3) * 16384 + (c & 7) * 2048 +
                           s * 32);
  };

  int c = cstart;
  stage(c, 0);
  f16x8 bc0 = bload(c, 0), bc1 = bload(c, 1);
  for (int it = 0; it < nIt; ++it) {
    const int par = it & 1;
    f16x8 bn0, bn1;
    if (it + 1 < nIt) {
      stage(c + 1, par ^ 1);
      bn0 = bload(c + 1, 0);
      bn1 = bload(c + 1, 1);
      WAITCNT_VM(4);  // next chunk's 2 GLL + 2 b-loads stay in flight
    } else {
      WAITCNT_VM(0);
    }
    __builtin_amdgcn_sched_barrier(0);
    const char* lb = lws + par * 2048;
    const f16x8 a0 = *(const f16x8*)(lb + offA0);
    acc = __builtin_amdgcn_mfma_f32_32x32x16_f16(a0, bc0, acc, 0, 0, 0);
    const f16x8 a1 = *(const f16x8*)(lb + offA1);
    acc = __builtin_amdgcn_mfma_f32_32x32x16_f16(a1, bc1, acc, 0, 0, 0);
    bc0 = bn0;
    bc1 = bn1;
    ++c;
  }

  // Block reduction over 4 waves. red[4][32][33] f32 = 16896 B.
  __syncthreads();
  float* red = (float*)smem;
  const int col = lane & 31;
  const int rowbase = 4 * h;
#pragma unroll
  for (int rI = 0; rI < 16; ++rI) {
    const int row = (rI & 3) + 8 * (rI >> 2) + rowbase;
    red[(wave * 32 + row) * 33 + col] = acc[rI];
  }
  __syncthreads();
  const int mm = tid >> 3;        // 0..31
  const int c0 = (tid & 7) * 4;   // 0..28
  float s0 = 0.f, s1 = 0.f, s2 = 0.f, s3 = 0.f;
#pragma unroll
  for (int w = 0; w < 4; ++w) {
    const float* rp = red + (w * 32 + mm) * 33 + c0;
    s0 += rp[0]; s1 += rp[1]; s2 += rp[2]; s3 += rp[3];
  }
  const f32x4 o4 = {s0, s1, s2, s3};
  *(f32x4*)&convp[(size_t)kg * 802816 + (size_t)(mtile * 32 + mm) * 32 + c0] = o4;
}

// ---------------------------------------------------------------------------
// Kernel 4: epilogue. v = sum(4 partials)+bias; sq=8v^2;
// scale = sq/((1+sq)*sqrt(sq+1e-8)); y=v*scale broadcast to 8 t-slots.
// ---------------------------------------------------------------------------
__global__ __launch_bounds__(256) void epilogue(const float* __restrict__ convp,
                                                const float* __restrict__ bias,
                                                float* __restrict__ out) {
  const int gi = blockIdx.x * 256 + threadIdx.x;  // 100352 total, exact grid
  const int base = gi * 8;
  const int p = gi >> 2;
  const int co0 = (gi & 3) * 8;
  const int bi = p / 784;
  const int pix = p - bi * 784;
  f32x4 v0 = {0.f, 0.f, 0.f, 0.f}, v1 = {0.f, 0.f, 0.f, 0.f};
#pragma unroll
  for (int qq = 0; qq < 4; ++qq) {
    v0 += *(const f32x4*)&convp[(size_t)qq * 802816 + base];
    v1 += *(const f32x4*)&convp[(size_t)qq * 802816 + base + 4];
  }
  float vb[8];
#pragma unroll
  for (int jj = 0; jj < 4; ++jj) {
    vb[jj] = v0[jj] + bias[co0 + jj];
    vb[4 + jj] = v1[jj] + bias[co0 + 4 + jj];
  }
  float* ob = out + (size_t)bi * 200704 + pix * 8;
#pragma unroll
  for (int jj = 0; jj < 8; ++jj) {
    const float vv = vb[jj];
    const float sq = 8.f * vv * vv;
    const float scale = sq / ((1.f + sq) * sqrtf(sq + 1e-8f));
    const float y = vv * scale;
    const f32x4 qv = {y, y, y, y};
    float* o = ob + (size_t)(co0 + jj) * 6272;
    *(f32x4*)o = qv;
    *(f32x4*)(o + 4) = qv;
  }
}

// ---------------------------------------------------------------------------
extern "C" void kernel_launch(void* const* d_in, const int* in_sizes, int n_in,
                              void* d_out, int out_size, void* d_ws,
                              size_t ws_size, hipStream_t stream) {
  const float* x = (const float*)d_in[0];     // [32,256,64,64]
  const float* W = (const float*)d_in[1];     // [32,256,9,9]
  const float* bias = (const float*)d_in[2];  // [32]
  float* out = (float*)d_out;                 // 6422528 f32

  char* ws = (char*)d_ws;
  f16* xt = (f16*)ws;                                // 67,108,864 B
  f16* wt = (f16*)(ws + 67108864);                   //  1,327,104 B
  float* convp = (float*)(ws + 67108864 + 1327104);  // 12,845,056 B (4 partials)

  nchw_to_nhwc_f16<<<dim3(2048), dim3(256), 0, stream>>>(x, xt);
  pack_w<<<dim3(64), dim3(256), 0, stream>>>(W, wt);
  conv_gemm<<<dim3(3136), dim3(256), 0, stream>>>(xt, wt, convp);
  epilogue<<<dim3(392), dim3(256), 0, stream>>>(convp, bias, out);
}

// Round 4
// 302.316 us; speedup vs baseline: 1.2251x; 1.2251x over previous
//
#include <hip/hip_runtime.h>
#include <hip/hip_bf16.h>
#include <stdint.h>

typedef _Float16 f16;
typedef _Float16 f16x8 __attribute__((ext_vector_type(8)));
typedef float f32x16 __attribute__((ext_vector_type(16)));
typedef float f32x4 __attribute__((ext_vector_type(4)));
typedef uint32_t u32x4 __attribute__((ext_vector_type(4)));
typedef uint32_t u32x2 __attribute__((ext_vector_type(2)));

// async global->LDS, 16B per lane, lands at ldsbase + lane*16 (wave-uniform base)
#define GLL16(gp, lp)                                                          \
  __builtin_amdgcn_global_load_lds(                                            \
      (const __attribute__((address_space(1))) void*)(gp),                     \
      (__attribute__((address_space(3))) void*)(lp), 16, 0, 0)

// s_waitcnt vmcnt(N), lgkm/exp unconstrained. gfx9 encoding.
#define WAITCNT_VM(N)                                                          \
  __builtin_amdgcn_s_waitcnt(((N)&0xF) | ((((N) >> 4) & 3) << 14) | 0x0F70)

// ---------------------------------------------------------------------------
// Kernel 1: x NCHW f32 [32,256,64,64] -> xt NHWC f16 [32,64,64,256]
// (unchanged from round 3 — correctness-proven)
// ---------------------------------------------------------------------------
__global__ __launch_bounds__(256) void nchw_to_nhwc_f16(
    const float* __restrict__ x, f16* __restrict__ xt) {
  __shared__ __align__(16) uint32_t tile[64 * 128];  // 32768 B
  const int bh = blockIdx.x;  // b*64 + h
  const int t = threadIdx.x;
  const float* src = x + (size_t)(bh >> 6) * (256 * 4096) + (bh & 63) * 64;

  const int w4 = t & 15;            // float4 index along w
  const int cq = t >> 4;            // c-quad 0..15
  const int xorv = 4 * (w4 & 7);    // = 4*((w>>2)&7) since w = w4*4+jw
#pragma unroll
  for (int it = 0; it < 4; ++it) {
    const int c0 = it * 64 + cq * 4;
    float4 v0 = *(const float4*)(src + (size_t)(c0 + 0) * 4096 + w4 * 4);
    float4 v1 = *(const float4*)(src + (size_t)(c0 + 1) * 4096 + w4 * 4);
    float4 v2 = *(const float4*)(src + (size_t)(c0 + 2) * 4096 + w4 * 4);
    float4 v3 = *(const float4*)(src + (size_t)(c0 + 3) * 4096 + w4 * 4);
    const float* p0 = (const float*)&v0;
    const float* p1 = (const float*)&v1;
    const float* p2 = (const float*)&v2;
    const float* p3 = (const float*)&v3;
    const int u = it * 32 + cq * 2;  // even word index (c-pair)
#pragma unroll
    for (int jw = 0; jw < 4; ++jw) {
      const int w = w4 * 4 + jw;
      f16 h0 = (f16)p0[jw], h1 = (f16)p1[jw], h2 = (f16)p2[jw], h3 = (f16)p3[jw];
      uint32_t lo = (uint32_t)__builtin_bit_cast(uint16_t, h0) |
                    ((uint32_t)__builtin_bit_cast(uint16_t, h1) << 16);
      uint32_t hi = (uint32_t)__builtin_bit_cast(uint16_t, h2) |
                    ((uint32_t)__builtin_bit_cast(uint16_t, h3) << 16);
      u32x2 pk = {lo, hi};
      *(u32x2*)&tile[w * 128 + (u ^ xorv)] = pk;
    }
  }
  __syncthreads();
  f16* dst = xt + (size_t)bh * 16384;
#pragma unroll
  for (int it = 0; it < 8; ++it) {
    const int idx = it * 256 + t;  // 0..2047 16B-granules
    const int w = idx >> 5;
    const int g = idx & 31;
    const u32x4 v = *(const u32x4*)&tile[w * 128 + ((g * 4) ^ (4 * ((w >> 2) & 7)))];
    *(u32x4*)(dst + idx * 8) = v;
  }
}

// ---------------------------------------------------------------------------
// Kernel 2: W [32co][256ci][9][9] f32 -> wt [81 kk][8 cic][32 co][32 ci] f16
// ---------------------------------------------------------------------------
__global__ __launch_bounds__(256) void pack_w(const float* __restrict__ W,
                                              f16* __restrict__ wt) {
  __shared__ float lds[10368];  // [128 ci][81 kk]
  const int t = threadIdx.x;
  const int co = blockIdx.x >> 1;
  const int cih = blockIdx.x & 1;
  const float* src = W + (size_t)(co * 256 + cih * 128) * 81;
  for (int i = t; i < 10368; i += 256) lds[i] = src[i];
  __syncthreads();
  for (int j = t; j < 1296; j += 256) {
    const int kk = j >> 4;
    const int t16 = j & 15;
    const int cicl = t16 >> 2;       // 0..3 (cic within half)
    const int ci8 = (t16 & 3) * 8;   // 0,8,16,24
    f16 tmp[8];
#pragma unroll
    for (int e = 0; e < 8; ++e)
      tmp[e] = (f16)lds[(cicl * 32 + ci8 + e) * 81 + kk];
    *(f16x8*)&wt[(size_t)kk * 8192 + (cih * 4 + cicl) * 1024 + co * 32 + ci8] =
        *(f16x8*)tmp;
  }
}

// ---------------------------------------------------------------------------
// Kernel 3: DIRECT conv, mfma_f32_32x32x16_f16, M=28 (one oh row, pad 32).
// 1792 blocks = 32 b x 28 oh x 2 ci-halves; 4 waves/block; wave owns
// cic = cih*4+wave (32 ci) for all 9 kh. Per slab (kh): stage ONE h-row
// (64w x 32ci = 4 KB) via 4 GLL16, then 9 kw taps x 2 k-phases read the SAME
// slab -> 4.5x less global A-traffic than im2col. Double-buffered slabs +
// 2-deep B register pipeline; hand-scheduled vmcnt; no K-loop barriers.
// LDS swizzle: slab byte F(w,g) = (w^((w>>1)&1))*64 + ((g^((w>>1)&3)))*16
// -> A-frag b128 reads hit all 8 bank-groups (minimal, 8 acc/bank).
// 32 KB LDS -> 5 blocks/CU (20 waves/CU).
// ---------------------------------------------------------------------------
__global__ __launch_bounds__(256, 5) void conv_direct(
    const f16* __restrict__ xt, const f16* __restrict__ wt,
    float* __restrict__ convp) {
  __shared__ __align__(16) char smem[32768];
  const int tid = threadIdx.x;
  const int lane = tid & 63;
  const int wave = tid >> 6;
  const int hh = lane >> 5;

  // Block -> (bimg, oh, cih), XCD-affine: xcd gets 4 consecutive images,
  // consecutive r = consecutive oh -> 7/9 input-row overlap served by L2.
  const int blk = blockIdx.x;
  const int xcd = blk & 7;
  const int r = blk >> 3;               // 0..223
  const int i4 = r / 56;                // 0..3
  const int rr = r - i4 * 56;
  const int bimg = xcd * 4 + i4;
  const int oh = rr >> 1;
  const int cih = rr & 1;
  const int cic = cih * 4 + wave;       // this wave's 32-ci chunk

  const char* xtb = (const char*)xt;
  const char* wtb = (const char*)wt;
  char* lws = smem + wave * 8192;       // 2 x 4096 slab buffers

  // --- staging address (lane-fixed): lane l writes LDS pos l*16 + i*1024.
  // pos (wp = l>>2 + 16i, gp = l&3) must contain row w = wp^((wp>>1)&1),
  // granule g = gp^((wp>>1)&3). (wp>>1)&1 and &3 are i-invariant.
  const int w_l = lane >> 2;
  const int u_l = w_l >> 1;
  const int gbase = ((w_l ^ (u_l & 1)) * 512) + (((lane & 3) ^ (u_l & 3)) * 16);

  auto stage = [&](int kh, int par) {
    const int h = 2 * oh + kh;          // 0..62
    const char* base = xtb + (size_t)((bimg * 4096 + h * 64) * 512 + cic * 64 + gbase);
    char* lb = lws + par * 4096;
    GLL16(base, lb);
    GLL16(base + 8192, lb + 1024);
    GLL16(base + 16384, lb + 2048);
    GLL16(base + 24576, lb + 3072);
  };

  // --- A-frag LDS offsets per kw (kh-invariant): row w = min(2m+kw, 63),
  // phase0 granule G = hh, phase1 = hh+2 (XOR 32 in swizzled bytes).
  const int m = lane & 31;
  int offA[9];
#pragma unroll
  for (int kw = 0; kw < 9; ++kw) {
    int w = 2 * m + kw;
    if (w > 63) w = 63;                 // pad rows read row 63 (discarded)
    const int u = w >> 1;
    offA[kw] = ((w ^ (u & 1)) * 64) + ((hh ^ (u & 3)) * 16);
  }

  // --- B fragment loads (L2-hot wt)
  const int bl = m * 64 + hh * 16 + cic * 2048;
  auto bload = [&](int kk, int s) -> f16x8 {
    return *(const f16x8*)(wtb + kk * 16384 + bl + s * 32);
  };

  f32x16 acc;
#pragma unroll
  for (int i = 0; i < 16; ++i) acc[i] = 0.f;

#define KW_ISSUE(KW, WC, KKN)                                                  \
  {                                                                            \
    const f16x8 bm0 = bload((KKN), 0);                                         \
    const f16x8 bm1 = bload((KKN), 1);                                         \
    WAITCNT_VM(WC);                                                            \
    __builtin_amdgcn_sched_barrier(0);                                         \
    const f16x8 a0 = *(const f16x8*)(lb + offA[KW]);                           \
    acc = __builtin_amdgcn_mfma_f32_32x32x16_f16(a0, bc0, acc, 0, 0, 0);       \
    const f16x8 a1 = *(const f16x8*)(lb + (offA[KW] ^ 32));                    \
    acc = __builtin_amdgcn_mfma_f32_32x32x16_f16(a1, bc1, acc, 0, 0, 0);       \
    bc0 = bn0; bc1 = bn1; bn0 = bm0; bn1 = bm1;                                \
  }
#define KW_NOISSUE(KW, WC)                                                     \
  {                                                                            \
    WAITCNT_VM(WC);                                                            \
    __builtin_amdgcn_sched_barrier(0);                                         \
    const f16x8 a0 = *(const f16x8*)(lb + offA[KW]);                           \
    acc = __builtin_amdgcn_mfma_f32_32x32x16_f16(a0, bc0, acc, 0, 0, 0);       \
    const f16x8 a1 = *(const f16x8*)(lb + (offA[KW] ^ 32));                    \
    acc = __builtin_amdgcn_mfma_f32_32x32x16_f16(a1, bc1, acc, 0, 0, 0);       \
    bc0 = bn0; bc1 = bn1;                                                      \
  }

  // Preamble. Queue after: [G0(4) B00(2) B01(2) G1(4)]
  stage(0, 0);
  f16x8 bc0 = bload(0, 0), bc1 = bload(0, 1);
  f16x8 bn0 = bload(1, 0), bn1 = bload(1, 1);
  stage(1, 1);

  // Slabs kh = 0..7. Steady-state queue entering slab kh:
  // [B(kh,0) B(kh,1) G(kh+1)] (8). kw0/kw1: wait(8); kw2: wait(4) drains
  // G(kh+1) (the once-per-slab prefetch stall); kw3..8: wait(4).
  for (int kh = 0; kh < 8; ++kh) {
    const char* lb = lws + (kh & 1) * 4096;
    const int kkb = kh * 9;
    KW_ISSUE(0, 8, kkb + 2)
    KW_ISSUE(1, 8, kkb + 3)
    KW_ISSUE(2, 4, kkb + 4)
    KW_ISSUE(3, 4, kkb + 5)
    KW_ISSUE(4, 4, kkb + 6)
    KW_ISSUE(5, 4, kkb + 7)
    KW_ISSUE(6, 4, kkb + 8)
    KW_ISSUE(7, 4, kkb + 9)   // B(kh+1, 0)
    KW_ISSUE(8, 4, kkb + 10)  // B(kh+1, 1)
    if (kh < 7) stage(kh + 2, kh & 1);
  }
  // Peeled slab kh=8 (par 0). Entering queue: [B80 B81].
  {
    const char* lb = lws;
    KW_ISSUE(0, 4, 74)
    KW_ISSUE(1, 4, 75)
    KW_ISSUE(2, 4, 76)
    KW_ISSUE(3, 4, 77)
    KW_ISSUE(4, 4, 78)
    KW_ISSUE(5, 4, 79)
    KW_ISSUE(6, 4, 80)
    KW_NOISSUE(7, 2)
    KW_NOISSUE(8, 0)
  }
#undef KW_ISSUE
#undef KW_NOISSUE

  // Block reduction over 4 waves. red[4][32][33] f32 = 16896 B.
  __syncthreads();
  float* red = (float*)smem;
#pragma unroll
  for (int rI = 0; rI < 16; ++rI) {
    const int row = (rI & 3) + 8 * (rI >> 2) + 4 * hh;
    red[(wave * 32 + row) * 33 + m] = acc[rI];
  }
  __syncthreads();
  const int mm = tid >> 3;        // 0..31 (ow)
  const int c0 = (tid & 7) * 4;   // 0..28
  if (mm < 28) {
    float s0 = 0.f, s1 = 0.f, s2 = 0.f, s3 = 0.f;
#pragma unroll
    for (int w = 0; w < 4; ++w) {
      const float* rp = red + (w * 32 + mm) * 33 + c0;
      s0 += rp[0]; s1 += rp[1]; s2 += rp[2]; s3 += rp[3];
    }
    const f32x4 o4 = {s0, s1, s2, s3};
    const int p = bimg * 784 + oh * 28 + mm;
    *(f32x4*)&convp[(size_t)cih * 802816 + (size_t)p * 32 + c0] = o4;
  }
}

// ---------------------------------------------------------------------------
// Kernel 4: epilogue. v = sum(2 partials)+bias; sq=8v^2;
// scale = sq/((1+sq)*sqrt(sq+1e-8)); y=v*scale broadcast to 8 t-slots.
// ---------------------------------------------------------------------------
__global__ __launch_bounds__(256) void epilogue(const float* __restrict__ convp,
                                                const float* __restrict__ bias,
                                                float* __restrict__ out) {
  const int gi = blockIdx.x * 256 + threadIdx.x;  // 100352 total, exact grid
  const int base = gi * 8;
  const int p = gi >> 2;
  const int co0 = (gi & 3) * 8;
  const int bi = p / 784;
  const int pix = p - bi * 784;
  f32x4 v0 = {0.f, 0.f, 0.f, 0.f}, v1 = {0.f, 0.f, 0.f, 0.f};
#pragma unroll
  for (int qq = 0; qq < 2; ++qq) {
    v0 += *(const f32x4*)&convp[(size_t)qq * 802816 + base];
    v1 += *(const f32x4*)&convp[(size_t)qq * 802816 + base + 4];
  }
  float vb[8];
#pragma unroll
  for (int jj = 0; jj < 4; ++jj) {
    vb[jj] = v0[jj] + bias[co0 + jj];
    vb[4 + jj] = v1[jj] + bias[co0 + 4 + jj];
  }
  float* ob = out + (size_t)bi * 200704 + pix * 8;
#pragma unroll
  for (int jj = 0; jj < 8; ++jj) {
    const float vv = vb[jj];
    const float sq = 8.f * vv * vv;
    const float scale = sq / ((1.f + sq) * sqrtf(sq + 1e-8f));
    const float y = vv * scale;
    const f32x4 qv = {y, y, y, y};
    float* o = ob + (size_t)(co0 + jj) * 6272;
    *(f32x4*)o = qv;
    *(f32x4*)(o + 4) = qv;
  }
}

// ---------------------------------------------------------------------------
extern "C" void kernel_launch(void* const* d_in, const int* in_sizes, int n_in,
                              void* d_out, int out_size, void* d_ws,
                              size_t ws_size, hipStream_t stream) {
  const float* x = (const float*)d_in[0];     // [32,256,64,64]
  const float* W = (const float*)d_in[1];     // [32,256,9,9]
  const float* bias = (const float*)d_in[2];  // [32]
  float* out = (float*)d_out;                 // 6422528 f32

  char* ws = (char*)d_ws;
  f16* xt = (f16*)ws;                                // 67,108,864 B
  f16* wt = (f16*)(ws + 67108864);                   //  1,327,104 B
  float* convp = (float*)(ws + 67108864 + 1327104);  //  6,422,528 B (2 halves)

  nchw_to_nhwc_f16<<<dim3(2048), dim3(256), 0, stream>>>(x, xt);
  pack_w<<<dim3(64), dim3(256), 0, stream>>>(W, wt);
  conv_direct<<<dim3(1792), dim3(256), 0, stream>>>(xt, wt, convp);
  epilogue<<<dim3(392), dim3(256), 0, stream>>>(convp, bias, out);
}

// Round 5
// 295.340 us; speedup vs baseline: 1.2540x; 1.0236x over previous
//
#include <hip/hip_runtime.h>
#include <hip/hip_bf16.h>
#include <stdint.h>

typedef _Float16 f16;
typedef _Float16 f16x8 __attribute__((ext_vector_type(8)));
typedef float f32x16 __attribute__((ext_vector_type(16)));
typedef float f32x4 __attribute__((ext_vector_type(4)));
typedef uint32_t u32x4 __attribute__((ext_vector_type(4)));
typedef uint32_t u32x2 __attribute__((ext_vector_type(2)));

#define MFMA(A, B, C) __builtin_amdgcn_mfma_f32_32x32x16_f16((A), (B), (C), 0, 0, 0)

// ---------------------------------------------------------------------------
// Kernel 1: x NCHW f32 [32,256,64,64] -> xt2 f16, MFMA-native layout:
//   16B unit U = ((((b*64+h)*8 + c32)*4 + g)*2 + (w&1))*32 + (w>>1)
//   (c = c32*32 + g*8 + e). A-fragment loads become contiguous 512B runs.
// Load phase unchanged from r4 (correctness-proven); write phase emits
// contiguous 16B units (n == local U), LDS reads conflict-free via swizzle.
// ---------------------------------------------------------------------------
__global__ __launch_bounds__(256) void nchw_to_nhwc_f16(
    const float* __restrict__ x, f16* __restrict__ xt) {
  __shared__ __align__(16) uint32_t tile[64 * 128];  // 32768 B
  const int bh = blockIdx.x;  // b*64 + h
  const int t = threadIdx.x;
  const float* src = x + (size_t)(bh >> 6) * (256 * 4096) + (bh & 63) * 64;

  const int w4 = t & 15;            // float4 index along w
  const int cq = t >> 4;            // c-quad 0..15
  const int xorv = 4 * (w4 & 7);    // = 4*((w>>2)&7) since w = w4*4+jw
#pragma unroll
  for (int it = 0; it < 4; ++it) {
    const int c0 = it * 64 + cq * 4;
    float4 v0 = *(const float4*)(src + (size_t)(c0 + 0) * 4096 + w4 * 4);
    float4 v1 = *(const float4*)(src + (size_t)(c0 + 1) * 4096 + w4 * 4);
    float4 v2 = *(const float4*)(src + (size_t)(c0 + 2) * 4096 + w4 * 4);
    float4 v3 = *(const float4*)(src + (size_t)(c0 + 3) * 4096 + w4 * 4);
    const float* p0 = (const float*)&v0;
    const float* p1 = (const float*)&v1;
    const float* p2 = (const float*)&v2;
    const float* p3 = (const float*)&v3;
    const int u = it * 32 + cq * 2;  // even word index (c-pair)
#pragma unroll
    for (int jw = 0; jw < 4; ++jw) {
      f16 h0 = (f16)p0[jw], h1 = (f16)p1[jw], h2 = (f16)p2[jw], h3 = (f16)p3[jw];
      uint32_t lo = (uint32_t)__builtin_bit_cast(uint16_t, h0) |
                    ((uint32_t)__builtin_bit_cast(uint16_t, h1) << 16);
      uint32_t hi = (uint32_t)__builtin_bit_cast(uint16_t, h2) |
                    ((uint32_t)__builtin_bit_cast(uint16_t, h3) << 16);
      u32x2 pk = {lo, hi};
      const int w = w4 * 4 + jw;
      *(u32x2*)&tile[w * 128 + (u ^ xorv)] = pk;
    }
  }
  __syncthreads();
  f16* dstb = xt + (size_t)bh * 16384;
#pragma unroll
  for (int it = 0; it < 8; ++it) {
    const int n = it * 256 + t;       // local 16B-unit index, 0..2047
    const int w2 = n & 31;
    const int par = (n >> 5) & 1;
    const int g8 = n >> 6;            // c-octet 0..31
    const int w = par + 2 * w2;
    const u32x4 v = *(const u32x4*)&tile[w * 128 + ((g8 * 4) ^ (4 * ((w >> 2) & 7)))];
    *(u32x4*)(dstb + n * 8) = v;
  }
}

// ---------------------------------------------------------------------------
// Kernel 2: W [32co][256ci][9][9] f32 -> wt2 f16:
//   byte = (((kk*8 + cic)*4 + sg)*32 + co)*16 + e*2,  ci = cic*32 + s*16+hh*8+e,
//   sg = s*2+hh. B-fragment loads become two contiguous 512B runs.
// ---------------------------------------------------------------------------
__global__ __launch_bounds__(256) void pack_w(const float* __restrict__ W,
                                              f16* __restrict__ wt) {
  __shared__ float lds[10368];  // [128 ci][81 kk]
  const int t = threadIdx.x;
  const int co = blockIdx.x >> 1;
  const int cih = blockIdx.x & 1;
  const float* src = W + (size_t)(co * 256 + cih * 128) * 81;
  for (int i = t; i < 10368; i += 256) lds[i] = src[i];
  __syncthreads();
  for (int j = t; j < 1296; j += 256) {
    const int kk = j >> 4;
    const int t16 = j & 15;
    const int cicl = t16 >> 2;       // cic within half, 0..3
    const int sg = t16 & 3;          // s*2 + hh
    const int cin = ((sg >> 1) & 1) * 16 + (sg & 1) * 8;  // ci offset in 32
    f16 tmp[8];
#pragma unroll
    for (int e = 0; e < 8; ++e)
      tmp[e] = (f16)lds[(cicl * 32 + cin + e) * 81 + kk];
    const int cic = cih * 4 + cicl;
    *(f16x8*)&wt[(size_t)(((kk * 8 + cic) * 4 + sg) * 32 + co) * 8] = *(f16x8*)tmp;
  }
}

// ---------------------------------------------------------------------------
// Kernel 3: direct conv, mfma_f32_32x32x16_f16, oh-PAIRED (M=64 via 2 acc).
// 896 blocks = 32 b x 14 ohp x 2 cih; 4 waves (cic = cih*4+wave).
// Slabs j=0..10 (input rows h=4ohp+j); tile T0 (oh=2ohp) active j<=8 (kh=j),
// T1 (oh=2ohp+1) active j>=2 (kh=j-2). A-frags SHARED by both tiles.
// NO LDS staging, NO manual waitcnt: all loads are compiler-tracked VGPR
// loads (fine-grained vmcnt, no FIFO coupling). Rolling depth-3 pipelines.
// A: contiguous 512B runs w/ immediate offsets, 9x in-wave reuse via L1/L2.
// LDS only for the 4-wave reduction (16.9 KB -> LDS-occupancy 9 blk/CU).
// ---------------------------------------------------------------------------
__global__ __launch_bounds__(256, 3) void conv_direct(
    const f16* __restrict__ xt, const f16* __restrict__ wt,
    float* __restrict__ convp) {
  __shared__ float red[4 * 32 * 33];  // 16896 B
  const int tid = threadIdx.x;
  const int lane = tid & 63;
  const int wave = tid >> 6;
  const int m = lane & 31;
  const int hh = lane >> 5;

  const int blk = blockIdx.x;
  const int xcd = blk & 7;
  const int r = blk >> 3;             // 0..111
  const int i4 = r / 28;              // 0..3
  const int rr = r - i4 * 28;
  const int bimg = xcd * 4 + i4;      // image on one XCD (L2 affinity)
  const int ohp = rr >> 1;            // 0..13
  const int cih = rr & 1;
  const int cic = cih * 4 + wave;     // this wave's 32-ci chunk (c32)

  const char* xb = (const char*)xt;
  const char* wb = (const char*)wt;

  // A lane base for slab j=0: byte = (bimg*64 + 4ohp)*32768 + cic*4096
  //                                  + hh*1024 + m*16 ; per slab += 32768.
  // In-slab offset: p*2048 + (kw&1)*512 + (kw>>1)*16  (max 2624, imm-safe).
  const char* ab = xb + ((size_t)(bimg * 64 + 4 * ohp) * 32768 +
                         cic * 4096 + hh * 1024 + m * 16);
  // B lane offset: cic*2048 + hh*512 + m*16 ; per (kk,s): kk*16384 + s*1024.
  const int boff = cic * 2048 + hh * 512 + m * 16;

#define ALOAD(AB, KW, P) \
  (*(const f16x8*)((AB) + (P) * 2048 + ((KW)&1) * 512 + ((KW) >> 1) * 16))
#define BLOAD(KK, S) \
  (*(const f16x8*)(wb + (size_t)(KK) * 16384 + (S) * 1024 + boff))

  f32x16 acc0, acc1;
#pragma unroll
  for (int i = 0; i < 16; ++i) { acc0[i] = 0.f; acc1[i] = 0.f; }

  // Slab body: rolling depth-3 register pipelines, compiler-managed waits.
#define SLAB_BODY(T0A, T1A, KKB0, KKB1)                                        \
  {                                                                            \
    f16x8 a0[3], a1[3], b00[3], b01[3], b10[3], b11[3];                        \
    _Pragma("unroll") for (int k = 0; k < 3; ++k) {                            \
      a0[k] = ALOAD(ab, k, 0);                                                 \
      a1[k] = ALOAD(ab, k, 1);                                                 \
      if (T0A) { b00[k] = BLOAD((KKB0) + k, 0); b01[k] = BLOAD((KKB0) + k, 1); } \
      if (T1A) { b10[k] = BLOAD((KKB1) + k, 0); b11[k] = BLOAD((KKB1) + k, 1); } \
    }                                                                          \
    _Pragma("unroll") for (int kw = 0; kw < 9; ++kw) {                         \
      const int sl = kw % 3;                                                   \
      const f16x8 ca0 = a0[sl], ca1 = a1[sl];                                  \
      f16x8 t00, t01, t10, t11;                                                \
      if (T0A) { t00 = b00[sl]; t01 = b01[sl]; }                               \
      if (T1A) { t10 = b10[sl]; t11 = b11[sl]; }                               \
      if (kw + 3 < 9) {                                                        \
        a0[sl] = ALOAD(ab, kw + 3, 0);                                         \
        a1[sl] = ALOAD(ab, kw + 3, 1);                                         \
        if (T0A) { b00[sl] = BLOAD((KKB0) + kw + 3, 0);                        \
                   b01[sl] = BLOAD((KKB0) + kw + 3, 1); }                      \
        if (T1A) { b10[sl] = BLOAD((KKB1) + kw + 3, 0);                        \
                   b11[sl] = BLOAD((KKB1) + kw + 3, 1); }                      \
      }                                                                        \
      if (T0A) { acc0 = MFMA(ca0, t00, acc0); acc0 = MFMA(ca1, t01, acc0); }   \
      if (T1A) { acc1 = MFMA(ca0, t10, acc1); acc1 = MFMA(ca1, t11, acc1); }   \
    }                                                                          \
  }

  for (int j = 0; j < 2; ++j) {            // T0 only (kh = j)
    SLAB_BODY(1, 0, j * 9, 0)
    ab += 32768;
  }
  for (int j = 2; j < 9; ++j) {            // both tiles
    SLAB_BODY(1, 1, j * 9, (j - 2) * 9)
    ab += 32768;
  }
  for (int j = 9; j < 11; ++j) {           // T1 only (kh = j-2)
    SLAB_BODY(0, 1, 0, (j - 2) * 9)
    ab += 32768;
  }
#undef SLAB_BODY
#undef ALOAD
#undef BLOAD

  // 4-wave reduction, two rounds (T0 -> oh=2ohp, T1 -> oh=2ohp+1).
  const int mm = tid >> 3;        // 0..31 (ow)
  const int c0 = (tid & 7) * 4;   // 0..28
#pragma unroll
  for (int half = 0; half < 2; ++half) {
    __syncthreads();
#pragma unroll
    for (int rI = 0; rI < 16; ++rI) {
      const int row = (rI & 3) + 8 * (rI >> 2) + 4 * hh;
      red[(wave * 32 + row) * 33 + m] = half ? acc1[rI] : acc0[rI];
    }
    __syncthreads();
    if (mm < 28) {
      float s0 = 0.f, s1 = 0.f, s2 = 0.f, s3 = 0.f;
#pragma unroll
      for (int w = 0; w < 4; ++w) {
        const float* rp = red + (w * 32 + mm) * 33 + c0;
        s0 += rp[0]; s1 += rp[1]; s2 += rp[2]; s3 += rp[3];
      }
      const f32x4 o4 = {s0, s1, s2, s3};
      const int p = bimg * 784 + (2 * ohp + half) * 28 + mm;
      *(f32x4*)&convp[(size_t)cih * 802816 + (size_t)p * 32 + c0] = o4;
    }
  }
}

// ---------------------------------------------------------------------------
// Kernel 4: epilogue. v = sum(2 partials)+bias; sq=8v^2;
// scale = sq/((1+sq)*sqrt(sq+1e-8)); y=v*scale broadcast to 8 t-slots.
// ---------------------------------------------------------------------------
__global__ __launch_bounds__(256) void epilogue(const float* __restrict__ convp,
                                                const float* __restrict__ bias,
                                                float* __restrict__ out) {
  const int gi = blockIdx.x * 256 + threadIdx.x;  // 100352 total, exact grid
  const int base = gi * 8;
  const int p = gi >> 2;
  const int co0 = (gi & 3) * 8;
  const int bi = p / 784;
  const int pix = p - bi * 784;
  f32x4 v0 = {0.f, 0.f, 0.f, 0.f}, v1 = {0.f, 0.f, 0.f, 0.f};
#pragma unroll
  for (int qq = 0; qq < 2; ++qq) {
    v0 += *(const f32x4*)&convp[(size_t)qq * 802816 + base];
    v1 += *(const f32x4*)&convp[(size_t)qq * 802816 + base + 4];
  }
  float vb[8];
#pragma unroll
  for (int jj = 0; jj < 4; ++jj) {
    vb[jj] = v0[jj] + bias[co0 + jj];
    vb[4 + jj] = v1[jj] + bias[co0 + 4 + jj];
  }
  float* ob = out + (size_t)bi * 200704 + pix * 8;
#pragma unroll
  for (int jj = 0; jj < 8; ++jj) {
    const float vv = vb[jj];
    const float sq = 8.f * vv * vv;
    const float scale = sq / ((1.f + sq) * sqrtf(sq + 1e-8f));
    const float y = vv * scale;
    const f32x4 qv = {y, y, y, y};
    float* o = ob + (size_t)(co0 + jj) * 6272;
    *(f32x4*)o = qv;
    *(f32x4*)(o + 4) = qv;
  }
}

// ---------------------------------------------------------------------------
extern "C" void kernel_launch(void* const* d_in, const int* in_sizes, int n_in,
                              void* d_out, int out_size, void* d_ws,
                              size_t ws_size, hipStream_t stream) {
  const float* x = (const float*)d_in[0];     // [32,256,64,64]
  const float* W = (const float*)d_in[1];     // [32,256,9,9]
  const float* bias = (const float*)d_in[2];  // [32]
  float* out = (float*)d_out;                 // 6422528 f32

  char* ws = (char*)d_ws;
  f16* xt = (f16*)ws;                                // 67,108,864 B
  f16* wt = (f16*)(ws + 67108864);                   //  1,327,104 B
  float* convp = (float*)(ws + 67108864 + 1327104);  //  6,422,528 B (2 halves)

  nchw_to_nhwc_f16<<<dim3(2048), dim3(256), 0, stream>>>(x, xt);
  pack_w<<<dim3(64), dim3(256), 0, stream>>>(W, wt);
  conv_direct<<<dim3(896), dim3(256), 0, stream>>>(xt, wt, convp);
  epilogue<<<dim3(392), dim3(256), 0, stream>>>(convp, bias, out);
}